// Round 9
// baseline (520.339 us; speedup 1.0000x reference)
//
#include <hip/hip_runtime.h>
#include <stdint.h>

#define N 8192
#define G 7
#define T 1024
#define NW 16         // waves per block
typedef uint32_t u32;
typedef uint16_t u16;

// Map float bits -> uint32 such that ascending uint order == DESCENDING float
// order, XLA total-order semantics. Stable LSD radix handles index tie-break.
__device__ __forceinline__ u32 enc_desc(float x) {
    u32 u = __float_as_uint(x);
    return (u & 0x80000000u) ? u : (~u & 0x7FFFFFFFu);
}
__device__ __forceinline__ float dec_desc(u32 k) {
    u32 u = (k & 0x80000000u) ? k : (~k & 0x7FFFFFFFu);
    return __uint_as_float(u);
}

// Digit d (0..255) -> u16 slot inside a 128-word per-wave counter row.
// Pairing d <-> d^0xAB (bit7 differs): word = (d&127) ^ ((d>>7)*0x2B),
// half = d>>7; the 12 hot pass-3 digits land in 12 distinct words (round 7).
__device__ __forceinline__ u32 dig_word(u32 d) { return (d & 127u) ^ ((d >> 7) * 0x2Bu); }
__device__ __forceinline__ u32 dig_col16(u32 d) { return (dig_word(d) << 1) | (d >> 7); }

// LDS: 32768(val) + 16384(idx) + 8192(wcnt, 16 waves x 128 words) + 16(wsum)
// = 57360 -> alloc 57856. x2 blocks = 115712, fits even a 128-KiB effective
// pool (rounds 6/7 proved 3x~53.5KiB never becomes resident; so target
// 32 waves/CU as 2 blocks x 16 waves instead of 3 x 8).
// NOTE: no min-occupancy arg in __launch_bounds__ — rounds 4/5 proved (T,k)
// pins the allocator and spills ~280 MB of scratch traffic.
__global__ __launch_bounds__(T) void portfolio_radix_kernel(
    const float* __restrict__ x,
    float* __restrict__ bc,        // [B, N] float32
    float* __restrict__ idx_out)   // [B, N] indices as float32
{
    __shared__ u32 val_s[N];          // 32 KiB  sort keys (enc values)
    __shared__ u16 idx_s[N];          // 16 KiB  payload indices (<8192)
    __shared__ u32 wcnt32[NW * 128];  // 8 KiB   per-wave digit counters (u16 halves)
    __shared__ u32 wsum[4];           // chunk totals for the 256-wide scan

    const int t    = threadIdx.x;
    const int w    = t >> 6;          // wave 0..15
    const int lane = t & 63;
    const int row  = blockIdx.x;
    const float* xr  = x + (size_t)row * N;
    float* bcr = bc + (size_t)row * N;
    float* ixr = idx_out + (size_t)row * N;

    u16* wcnt16 = (u16*)wcnt32;       // element view for scan/scatter reads

    // Element ownership e = 512*w + 64*j + lane: ownership order (w, j, lane)
    // == index order, matching rank composition wave-base + program-order +
    // ascending-lane atomic serialization (tie-stability validated round 3).
    u32 hi[8];                         // sort key per element
    u32 rni[8];                        // (idx<<16) | in-wave rank, per element
#pragma unroll
    for (int j = 0; j < 8; ++j) {
        int e = (w << 9) | (j << 6) | lane;
        hi[j] = enc_desc(xr[e]);
        // bc is zero except head/tail G; stream the zeros now so 134 MB of
        // global writes overlap the whole sort. Head/tail slots are written
        // by the SAME threads in the epilogue softmax (no cross-thread WAW).
        if (e >= G && e < N - G) bcr[e] = 0.0f;
    }
    // zero own wave's counter row (128 words); phase A touches only this row
    // from this wave -> no barrier needed before pass 0 (round-7 proven).
    wcnt32[(w << 7) + lane] = 0;
    wcnt32[(w << 7) + 64 + lane] = 0;

    for (int p = 0; p < 4; ++p) {
        const int shift = 8 * p;

        // ---- phase A (fused with gather for p>0): stable in-wave rank via
        // ds_add_rtn_u32 on u16 halves. Per-wave counts <= 512 -> no carry.
        // Ascending-lane same-address serialization (validated round 3).
        if (p == 0) {
#pragma unroll
            for (int j = 0; j < 8; ++j) {
                int e   = (w << 9) | (j << 6) | lane;
                u32 d   = hi[j] & 255u;
                u32 sh  = (d >> 7) << 4;
                u32 ret = atomicAdd(&wcnt32[(w << 7) + dig_word(d)], 1u << sh);
                rni[j]  = ((ret >> sh) & 0xFFFFu) | ((u32)e << 16);
            }
        } else {
#pragma unroll
            for (int j = 0; j < 8; ++j) {
                int e   = (w << 9) | (j << 6) | lane;
                hi[j]   = val_s[e];
                u32 iv  = (u32)idx_s[e];
                u32 d   = (hi[j] >> shift) & 255u;
                u32 sh  = (d >> 7) << 4;
                u32 ret = atomicAdd(&wcnt32[(w << 7) + dig_word(d)], 1u << sh);
                rni[j]  = ((ret >> sh) & 0xFFFFu) | (iv << 16);
            }
        }
        __syncthreads();                       // B1: all counts visible

        // ---- scan: threads 0..255 own one digit each. 16 INDEPENDENT u16
        // reads (latency-pipelined, no dependent round-trip chain), serial
        // exclusive scan in registers, 64-wide shuffle scan across digits,
        // fold chunk-internal base, write back per-wave bases. Chunk offsets
        // (wsum prefix) are applied by the scatter to save a barrier.
        if (t < 256) {
            const int col = (int)dig_col16((u32)t);
            u32 c[NW];
#pragma unroll
            for (int ww = 0; ww < NW; ++ww) c[ww] = (u32)wcnt16[(ww << 8) + col];
            u32 run = 0;
#pragma unroll
            for (int ww = 0; ww < NW; ++ww) { u32 cc = c[ww]; c[ww] = run; run += cc; }
            u32 v = run;                        // digit total; 64-wide scan
#pragma unroll
            for (int off = 1; off < 64; off <<= 1) {
                u32 u = __shfl_up(v, off, 64);
                if (lane >= off) v += u;
            }
            if (lane == 63) wsum[w] = v;        // chunk total (w = 0..3 here)
            u32 dbase = v - run;                // exclusive within chunk
#pragma unroll
            for (int ww = 0; ww < NW; ++ww)
                wcnt16[(ww << 8) + col] = (u16)(c[ww] + dbase);
        }
        __syncthreads();                       // B2: bases + wsum visible

        // ---- scatter (+ chunk offset from wsum) + re-zero own row ----
        {
            u32 s0 = wsum[0], s1 = wsum[1], s2 = wsum[2];   // broadcast reads
#pragma unroll
            for (int j = 0; j < 8; ++j) {
                u32 d    = (hi[j] >> shift) & 255u;
                u32 ch   = d >> 6;
                u32 coff = (ch > 0 ? s0 : 0u) + (ch > 1 ? s1 : 0u) + (ch > 2 ? s2 : 0u);
                u32 pos  = (rni[j] & 0xFFFFu)
                         + (u32)wcnt16[(w << 8) + dig_col16(d)] + coff;
                // last pass: only head/tail G values are ever read back
                if (p < 3 || pos < G || pos >= N - G) val_s[pos] = hi[j];
                idx_s[pos] = (u16)(rni[j] >> 16);
            }
        }
        // compiler fence: u32 zero-stores below must not hoist above the u16
        // base-reads in the scatter loop (mixed-width aliasing). Re-zero is
        // wave-private (own row only) -> no barrier needed before it.
        asm volatile("" ::: "memory");
        wcnt32[(w << 7) + lane] = 0;
        wcnt32[(w << 7) + 64 + lane] = 0;
        __syncthreads();                       // B3: scatter + re-zero done
    }

    // ---- outputs: idx_s holds final descending order's original indices ----
#pragma unroll
    for (int j = 0; j < 8; ++j) {
        int e = (w << 9) | (j << 6) | lane;     // coalesced stores
        ixr[e] = (float)idx_s[e];
    }
    // winner: threads 0..6 redundantly compute softmax(top-7), write own slot
    if (t < G) {
        float s[G], ex[G], sum = 0.f;
#pragma unroll
        for (int g = 0; g < G; ++g) s[g] = dec_desc(val_s[g]);
        float m0 = s[0];                        // max (descending values)
#pragma unroll
        for (int g = 0; g < G; ++g) { ex[g] = expf(s[g] - m0); sum += ex[g]; }
        bcr[t] = ex[t] / sum;
    }
    // loser: threads T-G..T-1 -> positions N-G..N-1.
    // -softmax(1 - bottom) == -softmax(-bottom) (shift invariance)
    if (t >= T - G) {
        float s[G], ex[G], sum = 0.f;
#pragma unroll
        for (int g = 0; g < G; ++g) s[g] = dec_desc(val_s[N - G + g]);
        float m0 = -s[G - 1];                   // max of -s (s descending)
#pragma unroll
        for (int g = 0; g < G; ++g) { ex[g] = expf(-s[g] - m0); sum += ex[g]; }
        bcr[(N - T) + t] = -ex[t - (T - G)] / sum;
    }
}

extern "C" void kernel_launch(void* const* d_in, const int* in_sizes, int n_in,
                              void* d_out, int out_size, void* d_ws, size_t ws_size,
                              hipStream_t stream) {
    const float* x = (const float*)d_in[0];
    float* out = (float*)d_out;
    const int B = in_sizes[0] / N;               // 4096
    float* bc  = out;                             // output 0: [B, N]
    float* idx = out + (size_t)B * N;             // output 1: [B, N] (as float32)
    portfolio_radix_kernel<<<B, T, 0, stream>>>(x, bc, idx);
}